// Round 1
// baseline (371.440 us; speedup 1.0000x reference)
//
#include <hip/hip_runtime.h>

// Problem constants (from reference)
#define Bc 4
#define Nc 16384
#define Hc 8
#define Dc 128
#define Kc 32
#define STRIDEc 16
#define Mc 1023  // (N-K)/STRIDE + 1 = 1023

// One block per (b, m). 256 threads = 8 h * 32 float4-lanes over D.
// out[b,m,h,d] = sum_k x[b, m*16+k, h, d] * w[k]/K  +  sum_k pe[k,d]*w[k]/K
__global__ __launch_bounds__(256) void compress_kv_kernel(
    const float* __restrict__ x,
    const float* __restrict__ w,
    const float* __restrict__ pe,
    float* __restrict__ out)
{
    __shared__ float s_w[Kc];
    __shared__ __align__(16) float s_bias[Dc];

    const int tid = threadIdx.x;

    // Stage weights (pre-divided by K) into LDS.
    if (tid < Kc) s_w[tid] = w[tid] * (1.0f / (float)Kc);
    __syncthreads();

    // Compute bias[d] = sum_k pe[k,d] * w[k]/K  (pe is 16 KB, L2-resident).
    if (tid < Dc) {
        float b = 0.0f;
        #pragma unroll 8
        for (int k = 0; k < Kc; ++k) b += pe[k * Dc + tid] * s_w[k];
        s_bias[tid] = b;
    }
    __syncthreads();

    const int bm = blockIdx.x;     // b*M + m
    const int m  = bm % Mc;
    const int b  = bm / Mc;
    const int d4 = tid & 31;       // float4 lane over D (D/4 = 32)
    const int h  = tid >> 5;       // 0..7

    const float4* __restrict__ x4 = (const float4*)x;

    // base in float4 units: ((b*N + m*16)*H + h) * (D/4) + d4
    int base = ((b * Nc + m * STRIDEc) * Hc + h) * (Dc / 4) + d4;
    const int step = Hc * (Dc / 4);   // one n-row in float4 units (256)

    float4 acc = ((const float4*)s_bias)[d4];

    #pragma unroll 8
    for (int k = 0; k < Kc; ++k) {
        float4 xv = x4[base + k * step];
        float wk = s_w[k];
        acc.x += xv.x * wk;
        acc.y += xv.y * wk;
        acc.z += xv.z * wk;
        acc.w += xv.w * wk;
    }

    float4* __restrict__ out4 = (float4*)out;
    const int obase = ((b * Mc + m) * Hc + h) * (Dc / 4) + d4;
    out4[obase] = acc;
}

extern "C" void kernel_launch(void* const* d_in, const int* in_sizes, int n_in,
                              void* d_out, int out_size, void* d_ws, size_t ws_size,
                              hipStream_t stream) {
    const float* x  = (const float*)d_in[0];
    const float* w  = (const float*)d_in[1];
    const float* pe = (const float*)d_in[2];
    float* out = (float*)d_out;

    const int grid = Bc * Mc;  // 4092 blocks
    compress_kv_kernel<<<grid, 256, 0, stream>>>(x, w, pe, out);
}